// Round 1
// baseline (120.341 us; speedup 1.0000x reference)
//
#include <hip/hip_runtime.h>
#include <hip/hip_bf16.h>

typedef __attribute__((ext_vector_type(4))) float f32x4;
typedef __attribute__((ext_vector_type(8))) short s16x8;

#define DEVI __device__ __forceinline__

constexpr int S = 512, C = 862, P = 96, H = 128, BATCH = 64;
constexpr int CT = 14;  // ceil(862/64)

DEVI short f2bf(float f) {
  unsigned u = __builtin_bit_cast(unsigned, f);
  u += 0x7fffu + ((u >> 16) & 1u);
  return (short)(u >> 16);
}

DEVI s16x8 mk8(const float* v) {
  s16x8 r;
#pragma unroll
  for (int i = 0; i < 8; ++i) r[i] = f2bf(v[i]);
  return r;
}

// ---------------- k0: weight conversions ----------------
__global__ __launch_bounds__(256) void k0_convert(
    const float* __restrict__ W1, const float* __restrict__ Wp,
    const float* __restrict__ W2, const float* __restrict__ mem,
    short* __restrict__ W1b, short* __restrict__ Wpb, short* __restrict__ W2b,
    short* __restrict__ memb, short* __restrict__ memTb) {
  int i = blockIdx.x * 256 + threadIdx.x;
  if (i < 65536) { W1b[i] = f2bf(W1[i]); return; }
  i -= 65536;
  if (i < 16384) { Wpb[i] = f2bf(Wp[i]); return; }
  i -= 16384;
  if (i < 24576) { W2b[i] = f2bf(W2[i]); return; }
  i -= 24576;
  if (i < 65536) {
    short v = f2bf(mem[i]);
    memb[i] = v;                              // [f][d]
    memTb[(i & 127) * 512 + (i >> 7)] = v;    // [d][f]
  }
}

// ---------------- k1: r1 = sigmoid(x^T W1^T + b1) ----------------
// grid (14, 64): x = c-tile, y = batch. 256 thr = 4 waves.
// Tile: 64 c x 128 h, K-step 64. LDS XOR-swizzle: phys_slot = slot ^ (row&7).
__global__ __launch_bounds__(256, 2) void k1_repre(
    const float* __restrict__ x, const short* __restrict__ W1b,
    const float* __restrict__ b1, short* __restrict__ R1b) {
  __shared__ short xt[64 * 64];    // [c][s] 8KB
  __shared__ short w1t[128 * 64];  // [h][s] 16KB
  const int b = blockIdx.y;
  const int c0 = blockIdx.x * 64;
  const int tid = threadIdx.x;
  const int l = tid & 63, w = tid >> 6;
  const int l15 = l & 15, l4 = l >> 4;
  const int csub = (w >> 1) * 32, hsub = (w & 1) * 64;

  f32x4 acc[2][4];
#pragma unroll
  for (int ct = 0; ct < 2; ++ct)
#pragma unroll
    for (int ht = 0; ht < 4; ++ht) acc[ct][ht] = (f32x4){0.f, 0.f, 0.f, 0.f};

  const int cme = tid & 63;
  const bool cv = (c0 + cme) < C;
  const float* xsrc0 = x + (size_t)b * S * C + c0 + cme;
  const int hh = tid >> 1, half = tid & 1;

  for (int kt = 0; kt < 8; ++kt) {
    __syncthreads();
    // stage x tile [64 c][64 s] transposed + bf16
#pragma unroll
    for (int j = 0; j < 2; ++j) {
      int o = (tid >> 6) + j * 4;  // s-octet 0..7
      float v[8];
      const float* src = xsrc0 + (size_t)(kt * 64 + o * 8) * C;
#pragma unroll
      for (int i = 0; i < 8; ++i) v[i] = cv ? src[(size_t)i * C] : 0.f;
      int phys = o ^ (cme & 7);
      *(s16x8*)&xt[cme * 64 + phys * 8] = mk8(v);
    }
    // stage W1 tile [128 h][64 s]
    {
      const short* wsrc = W1b + hh * 512 + kt * 64;
#pragma unroll
      for (int q = 0; q < 4; ++q) {
        int ss = half * 4 + q;
        s16x8 v = *(const s16x8*)&wsrc[ss * 8];
        int phys = ss ^ (hh & 7);
        *(s16x8*)&w1t[hh * 64 + phys * 8] = v;
      }
    }
    __syncthreads();
    s16x8 af[2][2], bf[4][2];
#pragma unroll
    for (int ct = 0; ct < 2; ++ct)
#pragma unroll
      for (int kc = 0; kc < 2; ++kc) {
        int row = csub + ct * 16 + l15;
        int slot = kc * 4 + l4;
        af[ct][kc] = *(const s16x8*)&xt[row * 64 + (slot ^ (row & 7)) * 8];
      }
#pragma unroll
    for (int ht = 0; ht < 4; ++ht)
#pragma unroll
      for (int kc = 0; kc < 2; ++kc) {
        int row = hsub + ht * 16 + l15;
        int slot = kc * 4 + l4;
        bf[ht][kc] = *(const s16x8*)&w1t[row * 64 + (slot ^ (row & 7)) * 8];
      }
#pragma unroll
    for (int ct = 0; ct < 2; ++ct)
#pragma unroll
      for (int ht = 0; ht < 4; ++ht)
#pragma unroll
        for (int kc = 0; kc < 2; ++kc)
          acc[ct][ht] = __builtin_amdgcn_mfma_f32_16x16x32_bf16(
              af[ct][kc], bf[ht][kc], acc[ct][ht], 0, 0, 0);
  }
  // epilogue: + b1, sigmoid, store bf16
#pragma unroll
  for (int ct = 0; ct < 2; ++ct) {
#pragma unroll
    for (int ht = 0; ht < 4; ++ht) {
      int hcol = hsub + ht * 16 + l15;
      float bias = b1[hcol];
#pragma unroll
      for (int e = 0; e < 4; ++e) {
        int crow = csub + ct * 16 + l4 * 4 + e;
        if (c0 + crow < C) {
          float v = acc[ct][ht][e] + bias;
          float sg = 1.f / (1.f + __expf(-v));
          R1b[((size_t)b * C + c0 + crow) * 128 + hcol] = f2bf(sg);
        }
      }
    }
  }
}

// ---------------- k2: fused projector + codebook attention + predictor ----------------
// grid (14, 64). 64 rows/block, 4 waves. Online softmax over 4 slices of 128.
__global__ __launch_bounds__(256, 2) void k2_fused(
    const short* __restrict__ R1b, const short* __restrict__ Wpb,
    const float* __restrict__ bp, const short* __restrict__ memb,
    const short* __restrict__ memTb, const short* __restrict__ W2b,
    const float* __restrict__ b2, float* __restrict__ out) {
  __shared__ short bufA[64 * 128];   // a1 -> pslice -> out_bf   (16KB)
  __shared__ short bufR2[64 * 128];  // r2 bf16                  (16KB)
  __shared__ short bmat[128 * 128];  // Wp -> mem slice -> f32 res (32KB)
  __shared__ float redsc[64];
  __shared__ float redsum[64];

  const int b = blockIdx.y, c0 = blockIdx.x * 64;
  const int valid = (C - c0 < 64) ? (C - c0) : 64;
  const int tid = threadIdx.x, l = tid & 63, w = tid >> 6;
  const int l15 = l & 15, l4 = l >> 4;
  const size_t n0 = (size_t)b * C + c0;

  // ---- stage a1 (r1 tile) and Wp ----
  {
    int r = tid >> 2, sg = tid & 3;
    const short* src = R1b + (n0 + r) * 128;
#pragma unroll
    for (int q = 0; q < 4; ++q) {
      int ss = sg * 4 + q;  // 0..15
      s16x8 v = {0, 0, 0, 0, 0, 0, 0, 0};
      if (r < valid) v = *(const s16x8*)&src[ss * 8];
      int phys = (ss & 8) | ((ss & 7) ^ (r & 7));
      *(s16x8*)&bufA[r * 128 + phys * 8] = v;
    }
    int j = tid >> 1, half = tid & 1;
    const short* wsrc = Wpb + j * 128;
#pragma unroll
    for (int q = 0; q < 8; ++q) {
      int ss = half * 8 + q;
      s16x8 v = *(const s16x8*)&wsrc[ss * 8];
      int phys = (ss & 8) | ((ss & 7) ^ (j & 7));
      *(s16x8*)&bmat[j * 128 + phys * 8] = v;
    }
  }
  __syncthreads();

  // ---- r2 = r1 @ Wp^T + bp  (wave w owns rows [16w,16w+16)) ----
  {
    s16x8 af[4];
#pragma unroll
    for (int kc = 0; kc < 4; ++kc) {
      int row = 16 * w + l15;
      int slot = kc * 4 + l4;
      int phys = (slot & 8) | ((slot & 7) ^ (row & 7));
      af[kc] = *(const s16x8*)&bufA[row * 128 + phys * 8];
    }
#pragma unroll
    for (int gt = 0; gt < 8; ++gt) {
      f32x4 acc = (f32x4){0.f, 0.f, 0.f, 0.f};
#pragma unroll
      for (int kc = 0; kc < 4; ++kc) {
        int row = gt * 16 + l15;
        int slot = kc * 4 + l4;
        int phys = (slot & 8) | ((slot & 7) ^ (row & 7));
        s16x8 bf = *(const s16x8*)&bmat[row * 128 + phys * 8];
        acc = __builtin_amdgcn_mfma_f32_16x16x32_bf16(af[kc], bf, acc, 0, 0, 0);
      }
      int g = gt * 16 + l15;
      float bias = bp[g];
#pragma unroll
      for (int e = 0; e < 4; ++e) {
        int row = 16 * w + l4 * 4 + e;
        bufR2[row * 128 + (g ^ ((row & 7) << 3))] = f2bf(acc[e] + bias);
      }
    }
  }

  float m_run[4], s_run[4];
#pragma unroll
  for (int e = 0; e < 4; ++e) { m_run[e] = -1e30f; s_run[e] = 0.f; }
  f32x4 oacc[4][2];
#pragma unroll
  for (int rt = 0; rt < 4; ++rt)
#pragma unroll
    for (int d = 0; d < 2; ++d) oacc[rt][d] = (f32x4){0.f, 0.f, 0.f, 0.f};

  for (int s = 0; s < 4; ++s) {
    __syncthreads();  // prior slice's bmat/pslice reads complete
    // stage mem slice [128 f][128 d]
    {
      int j = tid >> 1, half = tid & 1;
      const short* msrc = memb + (s * 128 + j) * 128;
#pragma unroll
      for (int q = 0; q < 8; ++q) {
        int ss = half * 8 + q;
        s16x8 v = *(const s16x8*)&msrc[ss * 8];
        int phys = (ss & 8) | ((ss & 7) ^ (j & 7));
        *(s16x8*)&bmat[j * 128 + phys * 8] = v;
      }
    }
    __syncthreads();
    // logits slice: rows [16w,16w+16) x 128 f
    f32x4 lg[8];
    {
      s16x8 af[4];
#pragma unroll
      for (int kc = 0; kc < 4; ++kc) {
        int row = 16 * w + l15;
        int slot = kc * 4 + l4;
        int phys = (slot & 8) | ((slot & 7) ^ (row & 7));
        af[kc] = *(const s16x8*)&bufR2[row * 128 + phys * 8];
      }
#pragma unroll
      for (int ft = 0; ft < 8; ++ft) {
        lg[ft] = (f32x4){0.f, 0.f, 0.f, 0.f};
#pragma unroll
        for (int kc = 0; kc < 4; ++kc) {
          int row = ft * 16 + l15;
          int slot = kc * 4 + l4;
          int phys = (slot & 8) | ((slot & 7) ^ (row & 7));
          s16x8 bf = *(const s16x8*)&bmat[row * 128 + phys * 8];
          lg[ft] = __builtin_amdgcn_mfma_f32_16x16x32_bf16(af[kc], bf, lg[ft], 0, 0, 0);
        }
      }
    }
    // online softmax update
#pragma unroll
    for (int e = 0; e < 4; ++e) {
      float mx = lg[0][e];
#pragma unroll
      for (int ft = 1; ft < 8; ++ft) mx = fmaxf(mx, lg[ft][e]);
      mx = fmaxf(mx, __shfl_xor(mx, 1));
      mx = fmaxf(mx, __shfl_xor(mx, 2));
      mx = fmaxf(mx, __shfl_xor(mx, 4));
      mx = fmaxf(mx, __shfl_xor(mx, 8));
      float mn = fmaxf(m_run[e], mx);
      float sc = __expf(m_run[e] - mn);
      float ps = 0.f;
#pragma unroll
      for (int ft = 0; ft < 8; ++ft) {
        float p = __expf(lg[ft][e] - mn);
        lg[ft][e] = p;
        ps += p;
      }
      ps += __shfl_xor(ps, 1);
      ps += __shfl_xor(ps, 2);
      ps += __shfl_xor(ps, 4);
      ps += __shfl_xor(ps, 8);
      s_run[e] = s_run[e] * sc + ps;
      m_run[e] = mn;
      int row = 16 * w + l4 * 4 + e;
      if (l15 == 0) redsc[row] = sc;
#pragma unroll
      for (int ft = 0; ft < 8; ++ft) {
        int fcol = ft * 16 + l15;
        bufA[row * 128 + (fcol ^ ((row & 7) << 3))] = f2bf(lg[ft][e]);
      }
    }
    __syncthreads();
    // PV: waves split d-columns; rescale then accumulate
#pragma unroll
    for (int rt = 0; rt < 4; ++rt)
#pragma unroll
      for (int e = 0; e < 4; ++e) {
        float sc = redsc[rt * 16 + l4 * 4 + e];
        oacc[rt][0][e] *= sc;
        oacc[rt][1][e] *= sc;
      }
#pragma unroll
    for (int rt = 0; rt < 4; ++rt) {
      s16x8 af[4];
#pragma unroll
      for (int kc = 0; kc < 4; ++kc) {
        int row = rt * 16 + l15;
        int slot = kc * 4 + l4;
        int phys = (slot & 8) | ((slot & 7) ^ (row & 7));
        af[kc] = *(const s16x8*)&bufA[row * 128 + phys * 8];
      }
#pragma unroll
      for (int dtl = 0; dtl < 2; ++dtl) {
        int d = (2 * w + dtl) * 16 + l15;
        const short* bsrc = memTb + d * 512 + s * 128;
#pragma unroll
        for (int kc = 0; kc < 4; ++kc) {
          s16x8 bf = *(const s16x8*)&bsrc[kc * 32 + l4 * 8];
          oacc[rt][dtl] = __builtin_amdgcn_mfma_f32_16x16x32_bf16(
              af[kc], bf, oacc[rt][dtl], 0, 0, 0);
        }
      }
    }
  }
  // final sums
#pragma unroll
  for (int e = 0; e < 4; ++e)
    if (l15 == 0) redsum[16 * w + l4 * 4 + e] = s_run[e];
  __syncthreads();
  // normalize, out -> bufA (bf16)
#pragma unroll
  for (int rt = 0; rt < 4; ++rt)
#pragma unroll
    for (int dtl = 0; dtl < 2; ++dtl) {
      int d = (2 * w + dtl) * 16 + l15;
#pragma unroll
      for (int e = 0; e < 4; ++e) {
        int row = rt * 16 + l4 * 4 + e;
        float v = oacc[rt][dtl][e] / redsum[row];
        bufA[row * 128 + (d ^ ((row & 7) << 3))] = f2bf(v);
      }
    }
  __syncthreads();
  // final GEMM: rep=[out|r2] @ W2^T + b2 ; waves take p-tiles {w, w+4}
  {
    float* resf = (float*)bmat;  // [64][97]
    f32x4 acc[4][2];
#pragma unroll
    for (int rt = 0; rt < 4; ++rt)
#pragma unroll
      for (int pt = 0; pt < 2; ++pt) acc[rt][pt] = (f32x4){0.f, 0.f, 0.f, 0.f};
#pragma unroll
    for (int rt = 0; rt < 4; ++rt) {
      s16x8 af[8];
#pragma unroll
      for (int kc = 0; kc < 8; ++kc) {
        int row = rt * 16 + l15;
        int slot = (kc & 3) * 4 + l4;
        int phys = (slot & 8) | ((slot & 7) ^ (row & 7));
        const short* bb = (kc < 4) ? bufA : bufR2;
        af[kc] = *(const s16x8*)&bb[row * 128 + phys * 8];
      }
#pragma unroll
      for (int pt = 0; pt < 2; ++pt) {
        int t = w + 4 * pt;
        if (t >= 6) continue;
        int p = t * 16 + l15;
        const short* bsrc = W2b + p * 256;
#pragma unroll
        for (int kc = 0; kc < 8; ++kc) {
          s16x8 bf = *(const s16x8*)&bsrc[kc * 32 + l4 * 8];
          acc[rt][pt] = __builtin_amdgcn_mfma_f32_16x16x32_bf16(
              af[kc], bf, acc[rt][pt], 0, 0, 0);
        }
      }
    }
#pragma unroll
    for (int rt = 0; rt < 4; ++rt)
#pragma unroll
      for (int pt = 0; pt < 2; ++pt) {
        int t = w + 4 * pt;
        if (t >= 6) continue;
        int p = t * 16 + l15;
        float bias = b2[p];
#pragma unroll
        for (int e = 0; e < 4; ++e) {
          int row = rt * 16 + l4 * 4 + e;
          resf[row * 97 + p] = acc[rt][pt][e] + bias;
        }
      }
  }
  __syncthreads();
  // coalesced transposed store
  {
    int c = tid & 63, p0 = tid >> 6;
    if (c < valid) {
      const float* resf = (const float*)bmat;
      float* dst = out + (size_t)b * P * C + c0 + c;
#pragma unroll
      for (int j = 0; j < 24; ++j) {
        int p = p0 + j * 4;
        dst[(size_t)p * C] = resf[c * 97 + p];
      }
    }
  }
}

extern "C" void kernel_launch(void* const* d_in, const int* in_sizes, int n_in,
                              void* d_out, int out_size, void* d_ws, size_t ws_size,
                              hipStream_t stream) {
  const float* x   = (const float*)d_in[0];
  const float* W1  = (const float*)d_in[1];
  const float* b1  = (const float*)d_in[2];
  const float* Wp  = (const float*)d_in[3];
  const float* bpv = (const float*)d_in[4];
  const float* W2  = (const float*)d_in[5];
  const float* b2  = (const float*)d_in[6];
  const float* mem = (const float*)d_in[7];
  char* ws = (char*)d_ws;
  short* W1b   = (short*)(ws);             // 131072 B
  short* Wpb   = (short*)(ws + 131072);    // 32768 B
  short* W2b   = (short*)(ws + 163840);    // 49152 B
  short* memb  = (short*)(ws + 212992);    // 131072 B
  short* memTb = (short*)(ws + 344064);    // 131072 B
  short* R1b   = (short*)(ws + 475136);    // 14123008 B
  float* outp = (float*)d_out;

  k0_convert<<<672, 256, 0, stream>>>(W1, Wp, W2, mem, W1b, Wpb, W2b, memb, memTb);
  dim3 grid(CT, BATCH);
  k1_repre<<<grid, 256, 0, stream>>>(x, W1b, b1, R1b);
  k2_fused<<<grid, 256, 0, stream>>>(R1b, Wpb, bpv, memb, memTb, W2b, b2, outp);
}